// Round 6
// baseline (481.363 us; speedup 1.0000x reference)
//
#include <hip/hip_runtime.h>
#include <cstdint>

// ---------- helpers ----------
typedef __attribute__((ext_vector_type(8))) short short8;   // 8 x bf16 (4 VGPRs)
typedef __attribute__((ext_vector_type(4))) float f32x4;

__device__ __forceinline__ float b2f(unsigned short u) {
    return __uint_as_float(((unsigned int)u) << 16);
}
__device__ __forceinline__ unsigned short f2b(float f) {   // RNE f32->bf16
    unsigned int u = __float_as_uint(f);
    u += 0x7FFFu + ((u >> 16) & 1u);
    return (unsigned short)(u >> 16);
}

// async global->LDS, 16B per lane; LDS dest is wave-uniform base + lane*16
__device__ __forceinline__ void gload_lds16(const unsigned short* g, unsigned short* l) {
    __builtin_amdgcn_global_load_lds(
        (const __attribute__((address_space(1))) uint32_t*)g,
        (__attribute__((address_space(3))) uint32_t*)l, 16, 0, 0);
}

// ---------- f32 device copy (residual pre-init for atomic GEMMs) ----------
__global__ __launch_bounds__(256) void k_copy(
        const float* __restrict__ src, float* __restrict__ dst, int n4) {
    int i = blockIdx.x * 256 + threadIdx.x;
    if (i < n4) ((float4*)dst)[i] = ((const float4*)src)[i];
}

// ---------- transpose + fp32->bf16 convert: w[K][N] -> wT[N][K] ----------
__global__ __launch_bounds__(256) void k_transpose_bf16(
        const float* __restrict__ w, unsigned short* __restrict__ wT, int K, int N) {
    __shared__ float tile[32][33];
    int n0 = blockIdx.x * 32, k0 = blockIdx.y * 32;
    int tx = threadIdx.x, ty = threadIdx.y;   // block (32,8)
#pragma unroll
    for (int i = 0; i < 4; i++)
        tile[ty + 8 * i][tx] = w[(size_t)(k0 + ty + 8 * i) * N + n0 + tx];
    __syncthreads();
#pragma unroll
    for (int i = 0; i < 4; i++)
        wT[(size_t)(n0 + ty + 8 * i) * K + k0 + tx] = f2b(tile[tx][ty + 8 * i]);
}

// ---------- layernorm (fp32 in, bf16 out), one row (C=1024) per block ----------
__global__ __launch_bounds__(256) void k_layernorm(
        const float* __restrict__ x, const float* __restrict__ w,
        unsigned short* __restrict__ out) {
    int row = blockIdx.x, tid = threadIdx.x;
    const float4* xr = (const float4*)(x + (size_t)row * 1024);
    float4 v = xr[tid];
    float s  = v.x + v.y + v.z + v.w;
    float ss = v.x * v.x + v.y * v.y + v.z * v.z + v.w * v.w;
#pragma unroll
    for (int off = 32; off >= 1; off >>= 1) {
        s  += __shfl_down(s, off);
        ss += __shfl_down(ss, off);
    }
    __shared__ float red[10];
    if ((tid & 63) == 0) { red[tid >> 6] = s; red[4 + (tid >> 6)] = ss; }
    __syncthreads();
    if (tid == 0) {
        float S  = red[0] + red[1] + red[2] + red[3];
        float SS = red[4] + red[5] + red[6] + red[7];
        float mu  = S * (1.0f / 1024.0f);
        float var = SS * (1.0f / 1024.0f) - mu * mu;
        red[8] = mu; red[9] = rsqrtf(var + 1e-5f);
    }
    __syncthreads();
    float mu = red[8], rs = red[9];
    float4 wv = ((const float4*)w)[tid];
    ushort4 pk;
    pk.x = f2b((v.x - mu) * rs * wv.x);
    pk.y = f2b((v.y - mu) * rs * wv.y);
    pk.z = f2b((v.z - mu) * rs * wv.z);
    pk.w = f2b((v.w - mu) * rs * wv.w);
    *(ushort4*)(out + (size_t)row * 1024 + tid * 4) = pk;
}

// ---------- bf16 MFMA GEMM: C[M][N] = A[M][K] @ BT[N][K]^T (+ epilogue) ----------
// BK=64, column-rotate LDS swizzle, global_load_lds. Wave-tile always 64x64.
// TM=128/TN=128: 2x2 waves. TM=256/TN=64: 4x1 waves (+ split-K via gridDim.z).
// EPI: 1 = bf16, 2 = RES + acc -> f32, 3 = gelu(acc) -> bf16, 4 = f32 atomicAdd
template <int EPI, int TM, int TN>
__global__ __launch_bounds__(256) void k_gemm_bt(
        const unsigned short* __restrict__ A, const unsigned short* __restrict__ BT,
        const float* __restrict__ RES, void* __restrict__ OUT,
        int M, int N, int K) {
    __shared__ __align__(16) unsigned short As[TM * 64];
    __shared__ __align__(16) unsigned short Bs[TN * 64];
    int tid  = threadIdx.x;
    int lane = tid & 63, wave = tid >> 6;
    int quad = lane >> 4, qr = lane & 15;
    int wm_off = (TM == 128) ? (wave >> 1) * 64 : wave * 64;
    int wn_off = (TM == 128) ? (wave & 1) * 64 : 0;
    int m0 = blockIdx.y * TM, n0 = blockIdx.x * TN;
    int ks = K / gridDim.z;                         // split-K slice
    int kbeg = blockIdx.z * ks, kend = kbeg + ks;
    // swizzle: logical col c of row r lives at lds col (c + 8*(r&7)) & 63
    int lrow = lane >> 3;                            // staging row within 8-row group
    int gcol = 8 * (((lane & 7) - lrow) & 7);        // staging source logical col
    int cswz[2];
#pragma unroll
    for (int kk = 0; kk < 2; kk++) cswz[kk] = 8 * (((kk * 4) + quad + (qr & 7)) & 7);
    f32x4 acc[4][4] = {};
    for (int k0 = kbeg; k0 < kend; k0 += 64) {
        __syncthreads();
#pragma unroll
        for (int t = 0; t < TM / 32; t++) {
            int rowb = wave * (TM / 4) + t * 8;
            gload_lds16(&A[(size_t)(m0 + rowb + lrow) * K + k0 + gcol], &As[rowb * 64]);
        }
#pragma unroll
        for (int t = 0; t < TN / 32; t++) {
            int rowb = wave * (TN / 4) + t * 8;
            gload_lds16(&BT[(size_t)(n0 + rowb + lrow) * K + k0 + gcol], &Bs[rowb * 64]);
        }
        __syncthreads();
#pragma unroll
        for (int kk = 0; kk < 2; kk++) {
            short8 af[4], bfr[4];
#pragma unroll
            for (int i = 0; i < 4; i++) af[i]  = *(const short8*)&As[(wm_off + i * 16 + qr) * 64 + cswz[kk]];
#pragma unroll
            for (int j = 0; j < 4; j++)  bfr[j] = *(const short8*)&Bs[(wn_off + j * 16 + qr) * 64 + cswz[kk]];
#pragma unroll
            for (int i = 0; i < 4; i++)
#pragma unroll
                for (int j = 0; j < 4; j++)
                    acc[i][j] = __builtin_amdgcn_mfma_f32_16x16x32_bf16(af[i], bfr[j], acc[i][j], 0, 0, 0);
        }
    }
    // epilogue: C/D layout col=lane&15, row=quad*4+reg
#pragma unroll
    for (int i = 0; i < 4; i++) {
#pragma unroll
        for (int j = 0; j < 4; j++) {
#pragma unroll
            for (int r = 0; r < 4; r++) {
                int row = m0 + wm_off + i * 16 + quad * 4 + r;
                int col = n0 + wn_off + j * 16 + qr;
                size_t idx = (size_t)row * N + col;
                float v = acc[i][j][r];
                if (EPI == 1)      ((unsigned short*)OUT)[idx] = f2b(v);
                else if (EPI == 2) ((float*)OUT)[idx] = RES[idx] + v;
                else if (EPI == 4) unsafeAtomicAdd(&((float*)OUT)[idx], v);
                else {
                    // tanh-form GELU via exp2: g = v*t/(t+1), t = 2^(2u/ln2)
                    float u = v * fmaf(v * v, 0.035677408f, 0.79788456f);
                    float e = fminf(u * 2.885390082f, 80.0f);   // guard inf/inf
                    float t = exp2f(e);
                    float g = v * t / (t + 1.0f);
                    ((unsigned short*)OUT)[idx] = f2b(g);
                }
            }
        }
    }
}

// ---------- MFMA causal flash attention, K-chunk=128, static-max softmax ------
// qkv bf16 [4096][3072] (q|k|v blocks of 1024 cols), out bf16 [4096][1024]
__global__ __launch_bounds__(256) void k_attn(
        const unsigned short* __restrict__ qkv, unsigned short* __restrict__ out) {
    __shared__ unsigned short Ks[128][72];      // K rows (Q staged here first)
    __shared__ unsigned short Vt[64][136];      // [dim][key 0..127], b128-aligned rows
    __shared__ unsigned short Ps[4][16][136];   // per wave [q][key 0..127] (wave-private)

    const float C1 = 0.18033688f;   // 0.125 * log2(e)
    const float C2 = 5.77078016f;   // 4.0   * log2(e)  (static max m=4)

    int l = blockIdx.x;                // 0..1023; big qb dispatched first
    int h = l & 15;
    int qb = 63 - (l >> 4);
    int q0 = qb * 64;

    int tid = threadIdx.x;
    int wave = tid >> 6, lane = tid & 63;
    int lane16 = lane & 15, quad = lane >> 4;
    bool even = !(lane16 & 1);

    // ---- stage Q through Ks rows 0..63, read loop-invariant A-frags ----
    {
        int srow = tid >> 2, sc0 = (tid & 3) * 16;
        size_t base = (size_t)(q0 + srow) * 3072 + h * 64 + sc0;
        *(uint4*)&Ks[srow][sc0]     = *(const uint4*)&qkv[base];
        *(uint4*)&Ks[srow][sc0 + 8] = *(const uint4*)&qkv[base + 8];
    }
    __syncthreads();
    short8 aq0 = *(const short8*)&Ks[wave * 16 + lane16][quad * 8];
    short8 aq1 = *(const short8*)&Ks[wave * 16 + lane16][32 + quad * 8];

    f32x4 Oacc[4] = {};                // lane holds O[q=quad*4+r][d=dt*16+lane16]
    float l_part[4] = {0.f, 0.f, 0.f, 0.f};

    int vk = (lane & 31) * 2;          // V staging: even local key
    int d0 = wave * 16 + (lane >> 5) * 8;

    for (int kc = 0; kc <= qb; kc += 2) {      // 128 keys per iteration
        __syncthreads();   // prev-iter LDS reads done (covers Q-frag reads at kc=0)
        {   // stage 128 K rows x 64 dims (coalesced b128)
            int srow = tid >> 1, c0 = (tid & 1) * 32;
            size_t base = (size_t)(kc * 64 + srow) * 3072 + 1024 + h * 64 + c0;
            *(uint4*)&Ks[srow][c0]      = *(const uint4*)&qkv[base];
            *(uint4*)&Ks[srow][c0 + 8]  = *(const uint4*)&qkv[base + 8];
            *(uint4*)&Ks[srow][c0 + 16] = *(const uint4*)&qkv[base + 16];
            *(uint4*)&Ks[srow][c0 + 24] = *(const uint4*)&qkv[base + 24];
        }
        {   // stage 128 V rows TRANSPOSED, key-pairs packed as b32 writes
#pragma unroll
            for (int c2 = 0; c2 < 2; c2++) {
                size_t vb = (size_t)((kc + c2) * 64 + vk) * 3072 + 2048 + h * 64 + d0;
                uint4 ve = *(const uint4*)&qkv[vb];
                uint4 vo = *(const uint4*)&qkv[vb + 3072];
                const unsigned short* pe = (const unsigned short*)&ve;
                const unsigned short* po = (const unsigned short*)&vo;
#pragma unroll
                for (int j = 0; j < 8; j++)
                    *(uint32_t*)&Vt[d0 + j][c2 * 64 + vk] =
                        (uint32_t)pe[j] | ((uint32_t)po[j] << 16);
            }
        }
        __syncthreads();

        // ---- S = Q K^T  (16q x 128k per wave) ----
        f32x4 sacc[8] = {};
#pragma unroll
        for (int kt = 0; kt < 8; kt++) {
            short8 bk0 = *(const short8*)&Ks[kt * 16 + lane16][quad * 8];
            short8 bk1 = *(const short8*)&Ks[kt * 16 + lane16][32 + quad * 8];
            sacc[kt] = __builtin_amdgcn_mfma_f32_16x16x32_bf16(aq0, bk0, sacc[kt], 0, 0, 0);
            sacc[kt] = __builtin_amdgcn_mfma_f32_16x16x32_bf16(aq1, bk1, sacc[kt], 0, 0, 0);
        }

        // ---- static-max softmax: p = 2^(s*C1 - C2); mask only on last chunk ----
        // Packed Ps writes: lane16-parity pairs exchange via shfl_xor(1) (DPP),
        // truncated bf16 pair -> one ds_write_b32; even lane writes r=0,1, odd r=2,3.
        bool domask = (kc + 2 > qb);   // wave-uniform
#pragma unroll
        for (int kt = 0; kt < 8; kt++) {
            uint32_t u[4];
#pragma unroll
            for (int r = 0; r < 4; r++) {
                float s = sacc[kt][r];
                if (domask) {
                    int key = kc * 64 + kt * 16 + lane16;
                    int qrow = q0 + wave * 16 + quad * 4 + r;
                    s = (key <= qrow) ? s : -__builtin_inff();
                }
                float p = exp2f(fmaf(s, C1, -C2));   // masked -> 0
                l_part[r] += p;
                u[r] = __float_as_uint(p);
            }
            // even lane sends u[2],u[3] (partner needs them), receives u[0],u[1]
            uint32_t t0 = __shfl_xor((int)(even ? u[2] : u[0]), 1);
            uint32_t t1 = __shfl_xor((int)(even ? u[3] : u[1]), 1);
            uint32_t lo0 = even ? u[0] : t0, hi0 = even ? t0 : u[2];
            uint32_t lo1 = even ? u[1] : t1, hi1 = even ? t1 : u[3];
            uint32_t w0 = (lo0 >> 16) | (hi0 & 0xFFFF0000u);
            uint32_t w1 = (lo1 >> 16) | (hi1 & 0xFFFF0000u);
            int rowb = quad * 4 + (even ? 0 : 2);
            int colp = kt * 16 + (lane16 & ~1);
            *(uint32_t*)&Ps[wave][rowb][colp]     = w0;
            *(uint32_t*)&Ps[wave][rowb + 1][colp] = w1;
        }
        // no barrier: Ps is wave-private; in-wave RAW handled by lgkmcnt

        // ---- O += P V  (A=P rows, B=V^T rows, both key-contiguous) ----
#pragma unroll
        for (int s = 0; s < 4; s++) {
            short8 ap = *(const short8*)&Ps[wave][lane16][s * 32 + quad * 8];
#pragma unroll
            for (int dt = 0; dt < 4; dt++) {
                short8 bv = *(const short8*)&Vt[dt * 16 + lane16][s * 32 + quad * 8];
                Oacc[dt] = __builtin_amdgcn_mfma_f32_16x16x32_bf16(ap, bv, Oacc[dt], 0, 0, 0);
            }
        }
    }

    // deferred l reduction (sum over lane16 key-group) + output
    float invl[4];
#pragma unroll
    for (int r = 0; r < 4; r++) {
        float lf = l_part[r];
        lf += __shfl_xor(lf, 1);
        lf += __shfl_xor(lf, 2);
        lf += __shfl_xor(lf, 4);
        lf += __shfl_xor(lf, 8);
        invl[r] = 1.0f / lf;
    }
#pragma unroll
    for (int dt = 0; dt < 4; dt++) {
#pragma unroll
        for (int r = 0; r < 4; r++) {
            int qrow = q0 + wave * 16 + quad * 4 + r;
            out[(size_t)qrow * 1024 + h * 64 + dt * 16 + lane16] = f2b(Oacc[dt][r] * invl[r]);
        }
    }
}

// ---------- launch ----------
extern "C" void kernel_launch(void* const* d_in, const int* in_sizes, int n_in,
                              void* d_out, int out_size, void* d_ws, size_t ws_size,
                              hipStream_t stream) {
    const float* x      = (const float*)d_in[0];
    const float* w_qkv  = (const float*)d_in[1];
    const float* w_attn = (const float*)d_in[2];
    const float* w_fc   = (const float*)d_in[3];
    const float* w_mlp  = (const float*)d_in[4];
    const float* ln1w   = (const float*)d_in[5];
    const float* ln2w   = (const float*)d_in[6];

    char* ws = (char*)d_ws;   // total 112 MB, no aliasing
    unsigned short* h      = (unsigned short*)(ws + 0);          //  8 MB
    unsigned short* wqkvT  = (unsigned short*)(ws + 8388608);    //  6 MB
    unsigned short* wattnT = (unsigned short*)(ws + 14680064);   //  2 MB
    unsigned short* wfcT   = (unsigned short*)(ws + 16777216);   //  8 MB
    unsigned short* wmlpT  = (unsigned short*)(ws + 25165824);   //  8 MB
    unsigned short* qkv    = (unsigned short*)(ws + 33554432);   // 24 MB
    unsigned short* attno  = (unsigned short*)(ws + 58720256);   //  8 MB
    float*          x2     = (float*)(ws + 67108864);            // 16 MB
    unsigned short* fcact  = (unsigned short*)(ws + 83886080);   // 32 MB
    float* outF = (float*)d_out;

    dim3 tb(32, 8);
    k_transpose_bf16<<<dim3(96, 32),  tb, 0, stream>>>(w_qkv,  wqkvT,  1024, 3072);
    k_transpose_bf16<<<dim3(32, 32),  tb, 0, stream>>>(w_attn, wattnT, 1024, 1024);
    k_transpose_bf16<<<dim3(128, 32), tb, 0, stream>>>(w_fc,   wfcT,   1024, 4096);
    k_transpose_bf16<<<dim3(32, 128), tb, 0, stream>>>(w_mlp,  wmlpT,  4096, 1024);

    k_layernorm<<<4096, 256, 0, stream>>>(x, ln1w, h);
    k_gemm_bt<1, 128, 128><<<dim3(24, 32), 256, 0, stream>>>(h, wqkvT, nullptr, qkv, 4096, 3072, 1024);
    k_copy<<<4096, 256, 0, stream>>>(x, x2, 1048576);   // residual pre-init (overlaps attn)
    k_attn<<<1024, 256, 0, stream>>>(qkv, attno);
    k_gemm_bt<4, 256, 64><<<dim3(16, 16, 2), 256, 0, stream>>>(attno, wattnT, nullptr, x2, 4096, 1024, 1024);
    k_layernorm<<<4096, 256, 0, stream>>>(x2, ln2w, h);
    k_copy<<<4096, 256, 0, stream>>>(x2, outF, 1048576);  // residual pre-init
    k_gemm_bt<3, 128, 128><<<dim3(32, 32), 256, 0, stream>>>(h, wfcT, nullptr, fcact, 4096, 4096, 1024);
    k_gemm_bt<4, 256, 64><<<dim3(16, 16, 4), 256, 0, stream>>>(fcact, wmlpT, nullptr, outF, 4096, 1024, 4096);
}

// Round 7
// 470.184 us; speedup vs baseline: 1.0238x; 1.0238x over previous
//
#include <hip/hip_runtime.h>
#include <cstdint>

// ---------- helpers ----------
typedef __attribute__((ext_vector_type(8))) short short8;   // 8 x bf16 (4 VGPRs)
typedef __attribute__((ext_vector_type(4))) float f32x4;

__device__ __forceinline__ float b2f(unsigned short u) {
    return __uint_as_float(((unsigned int)u) << 16);
}
__device__ __forceinline__ unsigned short f2b(float f) {   // RNE f32->bf16
    unsigned int u = __float_as_uint(f);
    u += 0x7FFFu + ((u >> 16) & 1u);
    return (unsigned short)(u >> 16);
}

// async global->LDS, 16B per lane; LDS dest is wave-uniform base + lane*16
__device__ __forceinline__ void gload_lds16(const unsigned short* g, unsigned short* l) {
    __builtin_amdgcn_global_load_lds(
        (const __attribute__((address_space(1))) uint32_t*)g,
        (__attribute__((address_space(3))) uint32_t*)l, 16, 0, 0);
}

// ---------- transpose + fp32->bf16 convert: w[K][N] -> wT[N][K] ----------
__global__ __launch_bounds__(256) void k_transpose_bf16(
        const float* __restrict__ w, unsigned short* __restrict__ wT, int K, int N) {
    __shared__ float tile[32][33];
    int n0 = blockIdx.x * 32, k0 = blockIdx.y * 32;
    int tx = threadIdx.x, ty = threadIdx.y;   // block (32,8)
#pragma unroll
    for (int i = 0; i < 4; i++)
        tile[ty + 8 * i][tx] = w[(size_t)(k0 + ty + 8 * i) * N + n0 + tx];
    __syncthreads();
#pragma unroll
    for (int i = 0; i < 4; i++)
        wT[(size_t)(n0 + ty + 8 * i) * K + k0 + tx] = f2b(tile[tx][ty + 8 * i]);
}

// ---------- layernorm (fp32 in, bf16 out), one row (C=1024) per block ----------
__global__ __launch_bounds__(256) void k_layernorm(
        const float* __restrict__ x, const float* __restrict__ w,
        unsigned short* __restrict__ out) {
    int row = blockIdx.x, tid = threadIdx.x;
    const float4* xr = (const float4*)(x + (size_t)row * 1024);
    float4 v = xr[tid];
    float s  = v.x + v.y + v.z + v.w;
    float ss = v.x * v.x + v.y * v.y + v.z * v.z + v.w * v.w;
#pragma unroll
    for (int off = 32; off >= 1; off >>= 1) {
        s  += __shfl_down(s, off);
        ss += __shfl_down(ss, off);
    }
    __shared__ float red[10];
    if ((tid & 63) == 0) { red[tid >> 6] = s; red[4 + (tid >> 6)] = ss; }
    __syncthreads();
    if (tid == 0) {
        float S  = red[0] + red[1] + red[2] + red[3];
        float SS = red[4] + red[5] + red[6] + red[7];
        float mu  = S * (1.0f / 1024.0f);
        float var = SS * (1.0f / 1024.0f) - mu * mu;
        red[8] = mu; red[9] = rsqrtf(var + 1e-5f);
    }
    __syncthreads();
    float mu = red[8], rs = red[9];
    float4 wv = ((const float4*)w)[tid];
    ushort4 pk;
    pk.x = f2b((v.x - mu) * rs * wv.x);
    pk.y = f2b((v.y - mu) * rs * wv.y);
    pk.z = f2b((v.z - mu) * rs * wv.z);
    pk.w = f2b((v.w - mu) * rs * wv.w);
    *(ushort4*)(out + (size_t)row * 1024 + tid * 4) = pk;
}

// ---------- bf16 MFMA GEMM: C[M][N] = A[M][K] @ BT[N][K]^T (+ epilogue) ----------
// BK=64, column-rotate LDS swizzle (conflict-free frag reads), global_load_lds.
// EPI: 1 = store bf16, 2 = RES + acc -> f32, 3 = gelu(acc) -> bf16
// TN: 128 (4 waves 64x64) or 64 (4 waves 32x64)
template <int EPI, int TN>
__global__ __launch_bounds__(256) void k_gemm_bt(
        const unsigned short* __restrict__ A, const unsigned short* __restrict__ BT,
        const float* __restrict__ RES, void* __restrict__ OUT,
        int M, int N, int K) {
    constexpr int MI = (TN == 128) ? 4 : 2;        // m-subtiles per wave
    __shared__ __align__(16) unsigned short As[128 * 64];
    __shared__ __align__(16) unsigned short Bs[TN * 64];
    int tid  = threadIdx.x;
    int lane = tid & 63, wave = tid >> 6;
    int quad = lane >> 4, qr = lane & 15;
    int wm_off = (TN == 128) ? (wave >> 1) * 64 : wave * 32;
    int wn_off = (TN == 128) ? (wave & 1) * 64 : 0;
    int m0 = blockIdx.y * 128, n0 = blockIdx.x * TN;
    // swizzle: logical col c of row r lives at lds col (c + 8*(r&7)) & 63
    int lrow = lane >> 3;                            // staging row within 8-row group
    int gcol = 8 * (((lane & 7) - lrow) & 7);        // staging source logical col
    int cswz[2];
#pragma unroll
    for (int kk = 0; kk < 2; kk++) cswz[kk] = 8 * (((kk * 4) + quad + (qr & 7)) & 7);
    f32x4 acc[MI][4] = {};
    for (int k0 = 0; k0 < K; k0 += 64) {
        __syncthreads();
#pragma unroll
        for (int t = 0; t < 4; t++) {                // A: 16 instrs, 4/wave
            int rowb = wave * 32 + t * 8;
            gload_lds16(&A[(size_t)(m0 + rowb + lrow) * K + k0 + gcol], &As[rowb * 64]);
        }
#pragma unroll
        for (int t = 0; t < TN / 32; t++) {          // B: TN/8 instrs
            int rowb = wave * (TN / 4) + t * 8;
            gload_lds16(&BT[(size_t)(n0 + rowb + lrow) * K + k0 + gcol], &Bs[rowb * 64]);
        }
        __syncthreads();
#pragma unroll
        for (int kk = 0; kk < 2; kk++) {
            short8 af[MI], bfr[4];
#pragma unroll
            for (int i = 0; i < MI; i++) af[i]  = *(const short8*)&As[(wm_off + i * 16 + qr) * 64 + cswz[kk]];
#pragma unroll
            for (int j = 0; j < 4; j++)  bfr[j] = *(const short8*)&Bs[(wn_off + j * 16 + qr) * 64 + cswz[kk]];
#pragma unroll
            for (int i = 0; i < MI; i++)
#pragma unroll
                for (int j = 0; j < 4; j++)
                    acc[i][j] = __builtin_amdgcn_mfma_f32_16x16x32_bf16(af[i], bfr[j], acc[i][j], 0, 0, 0);
        }
    }
    // epilogue: C/D layout col=lane&15, row=quad*4+reg
#pragma unroll
    for (int i = 0; i < MI; i++) {
#pragma unroll
        for (int j = 0; j < 4; j++) {
#pragma unroll
            for (int r = 0; r < 4; r++) {
                int row = m0 + wm_off + i * 16 + quad * 4 + r;
                int col = n0 + wn_off + j * 16 + qr;
                size_t idx = (size_t)row * N + col;
                float v = acc[i][j][r];
                if (EPI == 1)      ((unsigned short*)OUT)[idx] = f2b(v);
                else if (EPI == 2) ((float*)OUT)[idx] = RES[idx] + v;
                else {
                    // tanh-form GELU via exp2: g = v*t/(t+1), t = 2^(2u/ln2)
                    float u = v * fmaf(v * v, 0.035677408f, 0.79788456f);
                    float e = fminf(u * 2.885390082f, 80.0f);   // guard inf/inf
                    float t = exp2f(e);
                    float g = v * t / (t + 1.0f);
                    ((unsigned short*)OUT)[idx] = f2b(g);
                }
            }
        }
    }
}

// ---------- MFMA causal flash attention, TQ=128, K-chunk=128, static-max softmax
// qkv bf16 [4096][3072] (q|k|v blocks of 1024 cols), out bf16 [4096][1024]
// Block: one head, 128 q-rows; 4 waves x 32 q-rows (2 sequential 16-row sets).
__global__ __launch_bounds__(256) void k_attn(
        const unsigned short* __restrict__ qkv, unsigned short* __restrict__ out) {
    __shared__ unsigned short Ks[128][72];      // K rows (Q staged here first)
    __shared__ unsigned short Vt[64][136];      // [dim][key 0..127]
    __shared__ unsigned short Ps[4][16][136];   // per wave [q][key 0..127] (wave-private)

    const float C1 = 0.18033688f;   // 0.125 * log2(e)
    const float C2 = 5.77078016f;   // 4.0   * log2(e)  (static max m=4)

    int l = blockIdx.x;             // 0..511
    int h = l & 15;
    int i = l >> 4;                 // 0..31
    // anti-paired permutation: blocks i and i+16 (likely co-resident) sum to 31
    int qB = (i < 16) ? (31 - 2 * i) : (2 * (i - 16));
    int q0 = qB * 128;

    int tid = threadIdx.x;
    int wave = tid >> 6, lane = tid & 63;
    int lane16 = lane & 15, quad = lane >> 4;
    int srow = tid >> 1, sc0 = (tid & 1) * 32;   // 128-row staging coords

    // ---- stage 128 Q rows through Ks, read loop-invariant A-frags (2 sets) ----
    {
        size_t base = (size_t)(q0 + srow) * 3072 + h * 64 + sc0;
        *(uint4*)&Ks[srow][sc0]      = *(const uint4*)&qkv[base];
        *(uint4*)&Ks[srow][sc0 + 8]  = *(const uint4*)&qkv[base + 8];
        *(uint4*)&Ks[srow][sc0 + 16] = *(const uint4*)&qkv[base + 16];
        *(uint4*)&Ks[srow][sc0 + 24] = *(const uint4*)&qkv[base + 24];
    }
    __syncthreads();
    short8 aq[2][2];
#pragma unroll
    for (int s = 0; s < 2; s++) {
        aq[s][0] = *(const short8*)&Ks[wave * 32 + s * 16 + lane16][quad * 8];
        aq[s][1] = *(const short8*)&Ks[wave * 32 + s * 16 + lane16][32 + quad * 8];
    }

    f32x4 Oacc[2][4] = {};             // [set][d-tile]; O[q=quad*4+r][d=dt*16+lane16]
    float l_part[2][4] = {};

    int vk = (lane & 31) * 2;          // V staging: even local key
    int d0 = wave * 16 + (lane >> 5) * 8;

    for (int j = 0; j <= qB; j++) {    // 128 keys per iteration
        __syncthreads();   // prev-iter LDS reads done (covers Q-frag reads at j=0)
        {   // stage 128 K rows x 64 dims (coalesced b128)
            size_t base = (size_t)(j * 128 + srow) * 3072 + 1024 + h * 64 + sc0;
            *(uint4*)&Ks[srow][sc0]      = *(const uint4*)&qkv[base];
            *(uint4*)&Ks[srow][sc0 + 8]  = *(const uint4*)&qkv[base + 8];
            *(uint4*)&Ks[srow][sc0 + 16] = *(const uint4*)&qkv[base + 16];
            *(uint4*)&Ks[srow][sc0 + 24] = *(const uint4*)&qkv[base + 24];
        }
        {   // stage 128 V rows TRANSPOSED, key-pairs packed as b32 writes
#pragma unroll
            for (int c2 = 0; c2 < 2; c2++) {
                size_t vb = (size_t)(j * 128 + c2 * 64 + vk) * 3072 + 2048 + h * 64 + d0;
                uint4 ve = *(const uint4*)&qkv[vb];
                uint4 vo = *(const uint4*)&qkv[vb + 3072];
                const unsigned short* pe = (const unsigned short*)&ve;
                const unsigned short* po = (const unsigned short*)&vo;
#pragma unroll
                for (int jj = 0; jj < 8; jj++)
                    *(uint32_t*)&Vt[d0 + jj][c2 * 64 + vk] =
                        (uint32_t)pe[jj] | ((uint32_t)po[jj] << 16);
            }
        }
        __syncthreads();

        bool domask = (j == qB);       // wave-uniform: only diagonal chunk masks
#pragma unroll
        for (int s = 0; s < 2; s++) {  // two 16-row q-sets, sequential
            // ---- S = Q K^T  (16q x 128k) ----
            f32x4 sacc[8] = {};
#pragma unroll
            for (int kt = 0; kt < 8; kt++) {
                short8 bk0 = *(const short8*)&Ks[kt * 16 + lane16][quad * 8];
                short8 bk1 = *(const short8*)&Ks[kt * 16 + lane16][32 + quad * 8];
                sacc[kt] = __builtin_amdgcn_mfma_f32_16x16x32_bf16(aq[s][0], bk0, sacc[kt], 0, 0, 0);
                sacc[kt] = __builtin_amdgcn_mfma_f32_16x16x32_bf16(aq[s][1], bk1, sacc[kt], 0, 0, 0);
            }
            // ---- static-max softmax: p = 2^(s*C1 - C2) ----
#pragma unroll
            for (int r = 0; r < 4; r++) {
                int qrow = q0 + wave * 32 + s * 16 + quad * 4 + r;
#pragma unroll
                for (int kt = 0; kt < 8; kt++) {
                    float sv = sacc[kt][r];
                    if (domask) {
                        int key = j * 128 + kt * 16 + lane16;
                        sv = (key <= qrow) ? sv : -__builtin_inff();
                    }
                    float p = exp2f(fmaf(sv, C1, -C2));   // masked -> 0
                    l_part[s][r] += p;
                    Ps[wave][quad * 4 + r][kt * 16 + lane16] = f2b(p);
                }
            }
            // no barrier: Ps is wave-private; in-wave RAW ordered by lgkmcnt
            // ---- O += P V  (A=P rows, B=V^T rows, both key-contiguous) ----
#pragma unroll
            for (int ss = 0; ss < 4; ss++) {
                short8 ap = *(const short8*)&Ps[wave][lane16][ss * 32 + quad * 8];
#pragma unroll
                for (int dt = 0; dt < 4; dt++) {
                    short8 bv = *(const short8*)&Vt[dt * 16 + lane16][ss * 32 + quad * 8];
                    Oacc[s][dt] = __builtin_amdgcn_mfma_f32_16x16x32_bf16(ap, bv, Oacc[s][dt], 0, 0, 0);
                }
            }
        }
    }

    // deferred l reduction (sum over lane16 key-group) + output
#pragma unroll
    for (int s = 0; s < 2; s++) {
        float invl[4];
#pragma unroll
        for (int r = 0; r < 4; r++) {
            float lf = l_part[s][r];
            lf += __shfl_xor(lf, 1);
            lf += __shfl_xor(lf, 2);
            lf += __shfl_xor(lf, 4);
            lf += __shfl_xor(lf, 8);
            invl[r] = 1.0f / lf;
        }
#pragma unroll
        for (int dt = 0; dt < 4; dt++) {
#pragma unroll
            for (int r = 0; r < 4; r++) {
                int qrow = q0 + wave * 32 + s * 16 + quad * 4 + r;
                out[(size_t)qrow * 1024 + h * 64 + dt * 16 + lane16] = f2b(Oacc[s][dt][r] * invl[r]);
            }
        }
    }
}

// ---------- launch ----------
extern "C" void kernel_launch(void* const* d_in, const int* in_sizes, int n_in,
                              void* d_out, int out_size, void* d_ws, size_t ws_size,
                              hipStream_t stream) {
    const float* x      = (const float*)d_in[0];
    const float* w_qkv  = (const float*)d_in[1];
    const float* w_attn = (const float*)d_in[2];
    const float* w_fc   = (const float*)d_in[3];
    const float* w_mlp  = (const float*)d_in[4];
    const float* ln1w   = (const float*)d_in[5];
    const float* ln2w   = (const float*)d_in[6];

    char* ws = (char*)d_ws;   // total 112 MB, no aliasing
    unsigned short* h      = (unsigned short*)(ws + 0);          //  8 MB
    unsigned short* wqkvT  = (unsigned short*)(ws + 8388608);    //  6 MB
    unsigned short* wattnT = (unsigned short*)(ws + 14680064);   //  2 MB
    unsigned short* wfcT   = (unsigned short*)(ws + 16777216);   //  8 MB
    unsigned short* wmlpT  = (unsigned short*)(ws + 25165824);   //  8 MB
    unsigned short* qkv    = (unsigned short*)(ws + 33554432);   // 24 MB
    unsigned short* attno  = (unsigned short*)(ws + 58720256);   //  8 MB
    float*          x2     = (float*)(ws + 67108864);            // 16 MB
    unsigned short* fcact  = (unsigned short*)(ws + 83886080);   // 32 MB
    float* outF = (float*)d_out;

    dim3 tb(32, 8);
    k_transpose_bf16<<<dim3(96, 32),  tb, 0, stream>>>(w_qkv,  wqkvT,  1024, 3072);
    k_transpose_bf16<<<dim3(32, 32),  tb, 0, stream>>>(w_attn, wattnT, 1024, 1024);
    k_transpose_bf16<<<dim3(128, 32), tb, 0, stream>>>(w_fc,   wfcT,   1024, 4096);
    k_transpose_bf16<<<dim3(32, 128), tb, 0, stream>>>(w_mlp,  wmlpT,  4096, 1024);

    k_layernorm<<<4096, 256, 0, stream>>>(x, ln1w, h);
    k_gemm_bt<1, 128><<<dim3(24, 32), 256, 0, stream>>>(h, wqkvT, nullptr, qkv, 4096, 3072, 1024);
    k_attn<<<512, 256, 0, stream>>>(qkv, attno);
    k_gemm_bt<2, 64><<<dim3(16, 32), 256, 0, stream>>>(attno, wattnT, x, x2, 4096, 1024, 1024);
    k_layernorm<<<4096, 256, 0, stream>>>(x2, ln2w, h);
    k_gemm_bt<3, 128><<<dim3(32, 32), 256, 0, stream>>>(h, wfcT, nullptr, fcact, 4096, 4096, 1024);
    k_gemm_bt<2, 64><<<dim3(16, 32), 256, 0, stream>>>(fcact, wmlpT, x2, outF, 4096, 1024, 4096);
}

// Round 8
// 373.239 us; speedup vs baseline: 1.2897x; 1.2597x over previous
//
#include <hip/hip_runtime.h>
#include <cstdint>

// ---------- helpers ----------
typedef __attribute__((ext_vector_type(8))) short short8;   // 8 x bf16 (4 VGPRs)
typedef __attribute__((ext_vector_type(4))) float f32x4;

__device__ __forceinline__ float b2f(unsigned short u) {
    return __uint_as_float(((unsigned int)u) << 16);
}
__device__ __forceinline__ unsigned short f2b(float f) {   // RNE f32->bf16
    unsigned int u = __float_as_uint(f);
    u += 0x7FFFu + ((u >> 16) & 1u);
    return (unsigned short)(u >> 16);
}

// async global->LDS, 16B per lane; LDS dest is wave-uniform base + lane*16
__device__ __forceinline__ void gload_lds16(const unsigned short* g, unsigned short* l) {
    __builtin_amdgcn_global_load_lds(
        (const __attribute__((address_space(1))) uint32_t*)g,
        (__attribute__((address_space(3))) uint32_t*)l, 16, 0, 0);
}

// ---------- transpose + fp32->bf16 convert: w[K][N] -> wT[N][K] ----------
__global__ __launch_bounds__(256) void k_transpose_bf16(
        const float* __restrict__ w, unsigned short* __restrict__ wT, int K, int N) {
    __shared__ float tile[32][33];
    int n0 = blockIdx.x * 32, k0 = blockIdx.y * 32;
    int tx = threadIdx.x, ty = threadIdx.y;   // block (32,8)
#pragma unroll
    for (int i = 0; i < 4; i++)
        tile[ty + 8 * i][tx] = w[(size_t)(k0 + ty + 8 * i) * N + n0 + tx];
    __syncthreads();
#pragma unroll
    for (int i = 0; i < 4; i++)
        wT[(size_t)(n0 + ty + 8 * i) * K + k0 + tx] = f2b(tile[tx][ty + 8 * i]);
}

// ---------- layernorm (fp32 in, bf16 out), one row (C=1024) per block ----------
__global__ __launch_bounds__(256) void k_layernorm(
        const float* __restrict__ x, const float* __restrict__ w,
        unsigned short* __restrict__ out) {
    int row = blockIdx.x, tid = threadIdx.x;
    const float4* xr = (const float4*)(x + (size_t)row * 1024);
    float4 v = xr[tid];
    float s  = v.x + v.y + v.z + v.w;
    float ss = v.x * v.x + v.y * v.y + v.z * v.z + v.w * v.w;
#pragma unroll
    for (int off = 32; off >= 1; off >>= 1) {
        s  += __shfl_down(s, off);
        ss += __shfl_down(ss, off);
    }
    __shared__ float red[10];
    if ((tid & 63) == 0) { red[tid >> 6] = s; red[4 + (tid >> 6)] = ss; }
    __syncthreads();
    if (tid == 0) {
        float S  = red[0] + red[1] + red[2] + red[3];
        float SS = red[4] + red[5] + red[6] + red[7];
        float mu  = S * (1.0f / 1024.0f);
        float var = SS * (1.0f / 1024.0f) - mu * mu;
        red[8] = mu; red[9] = rsqrtf(var + 1e-5f);
    }
    __syncthreads();
    float mu = red[8], rs = red[9];
    float4 wv = ((const float4*)w)[tid];
    ushort4 pk;
    pk.x = f2b((v.x - mu) * rs * wv.x);
    pk.y = f2b((v.y - mu) * rs * wv.y);
    pk.z = f2b((v.z - mu) * rs * wv.z);
    pk.w = f2b((v.w - mu) * rs * wv.w);
    *(ushort4*)(out + (size_t)row * 1024 + tid * 4) = pk;
}

// ---------- bf16 MFMA GEMM: C[M][N] = A[M][K] @ BT[N][K]^T (+ epilogue) ----------
// BK=64, column-rotate LDS swizzle (conflict-free frag reads), global_load_lds.
// EPI: 1 = store bf16, 2 = RES + acc -> f32, 3 = gelu(acc) -> bf16
// TN: 128 (4 waves 64x64) or 64 (4 waves 32x64)
template <int EPI, int TN>
__global__ __launch_bounds__(256) void k_gemm_bt(
        const unsigned short* __restrict__ A, const unsigned short* __restrict__ BT,
        const float* __restrict__ RES, void* __restrict__ OUT,
        int M, int N, int K) {
    constexpr int MI = (TN == 128) ? 4 : 2;        // m-subtiles per wave
    __shared__ __align__(16) unsigned short As[128 * 64];
    __shared__ __align__(16) unsigned short Bs[TN * 64];
    int tid  = threadIdx.x;
    int lane = tid & 63, wave = tid >> 6;
    int quad = lane >> 4, qr = lane & 15;
    int wm_off = (TN == 128) ? (wave >> 1) * 64 : wave * 32;
    int wn_off = (TN == 128) ? (wave & 1) * 64 : 0;
    int m0 = blockIdx.y * 128, n0 = blockIdx.x * TN;
    // swizzle: logical col c of row r lives at lds col (c + 8*(r&7)) & 63
    int lrow = lane >> 3;                            // staging row within 8-row group
    int gcol = 8 * (((lane & 7) - lrow) & 7);        // staging source logical col
    int cswz[2];
#pragma unroll
    for (int kk = 0; kk < 2; kk++) cswz[kk] = 8 * (((kk * 4) + quad + (qr & 7)) & 7);
    f32x4 acc[MI][4] = {};
    for (int k0 = 0; k0 < K; k0 += 64) {
        __syncthreads();
#pragma unroll
        for (int t = 0; t < 4; t++) {                // A: 16 instrs, 4/wave
            int rowb = wave * 32 + t * 8;
            gload_lds16(&A[(size_t)(m0 + rowb + lrow) * K + k0 + gcol], &As[rowb * 64]);
        }
#pragma unroll
        for (int t = 0; t < TN / 32; t++) {          // B: TN/8 instrs
            int rowb = wave * (TN / 4) + t * 8;
            gload_lds16(&BT[(size_t)(n0 + rowb + lrow) * K + k0 + gcol], &Bs[rowb * 64]);
        }
        __syncthreads();
#pragma unroll
        for (int kk = 0; kk < 2; kk++) {
            short8 af[MI], bfr[4];
#pragma unroll
            for (int i = 0; i < MI; i++) af[i]  = *(const short8*)&As[(wm_off + i * 16 + qr) * 64 + cswz[kk]];
#pragma unroll
            for (int j = 0; j < 4; j++)  bfr[j] = *(const short8*)&Bs[(wn_off + j * 16 + qr) * 64 + cswz[kk]];
#pragma unroll
            for (int i = 0; i < MI; i++)
#pragma unroll
                for (int j = 0; j < 4; j++)
                    acc[i][j] = __builtin_amdgcn_mfma_f32_16x16x32_bf16(af[i], bfr[j], acc[i][j], 0, 0, 0);
        }
    }
    // epilogue: C/D layout col=lane&15, row=quad*4+reg
#pragma unroll
    for (int i = 0; i < MI; i++) {
#pragma unroll
        for (int j = 0; j < 4; j++) {
#pragma unroll
            for (int r = 0; r < 4; r++) {
                int row = m0 + wm_off + i * 16 + quad * 4 + r;
                int col = n0 + wn_off + j * 16 + qr;
                size_t idx = (size_t)row * N + col;
                float v = acc[i][j][r];
                if (EPI == 1)      ((unsigned short*)OUT)[idx] = f2b(v);
                else if (EPI == 2) ((float*)OUT)[idx] = RES[idx] + v;
                else {
                    // tanh-form GELU via exp2: g = v*t/(t+1), t = 2^(2u/ln2)
                    float u = v * fmaf(v * v, 0.035677408f, 0.79788456f);
                    float e = fminf(u * 2.885390082f, 80.0f);   // guard inf/inf
                    float t = exp2f(e);
                    float g = v * t / (t + 1.0f);
                    ((unsigned short*)OUT)[idx] = f2b(g);
                }
            }
        }
    }
}

// ---------- MFMA causal flash attention, K-chunk=128, static-max softmax ------
// Register-prefetch pipeline: chunk j+2's global loads issue after the staging
// barrier and overlap chunk j's compute; regs -> LDS next iteration.
// qkv bf16 [4096][3072] (q|k|v blocks of 1024 cols), out bf16 [4096][1024]
__global__ __launch_bounds__(256) void k_attn(
        const unsigned short* __restrict__ qkv, unsigned short* __restrict__ out) {
    __shared__ unsigned short Ks[128][72];      // K rows (Q staged here first)
    __shared__ unsigned short Vt[64][136];      // [dim][key 0..127]
    __shared__ unsigned short Ps[4][16][136];   // per wave [q][key 0..127] (wave-private)

    const float C1 = 0.18033688f;   // 0.125 * log2(e)
    const float C2 = 5.77078016f;   // 4.0   * log2(e)  (static max m=4)

    int l = blockIdx.x;                // 0..1023; big qb dispatched first
    int h = l & 15;
    int qb = 63 - (l >> 4);
    int q0 = qb * 64;

    int tid = threadIdx.x;
    int wave = tid >> 6, lane = tid & 63;
    int lane16 = lane & 15, quad = lane >> 4;

    // ---- stage Q through Ks rows 0..63, read loop-invariant A-frags ----
    {
        int srow = tid >> 2, sc0 = (tid & 3) * 16;
        size_t base = (size_t)(q0 + srow) * 3072 + h * 64 + sc0;
        *(uint4*)&Ks[srow][sc0]     = *(const uint4*)&qkv[base];
        *(uint4*)&Ks[srow][sc0 + 8] = *(const uint4*)&qkv[base + 8];
    }
    __syncthreads();
    short8 aq0 = *(const short8*)&Ks[wave * 16 + lane16][quad * 8];
    short8 aq1 = *(const short8*)&Ks[wave * 16 + lane16][32 + quad * 8];

    f32x4 Oacc[4] = {};                // lane holds O[q=quad*4+r][d=dt*16+lane16]
    float l_part[4] = {0.f, 0.f, 0.f, 0.f};

    int srow = tid >> 1, sc0 = (tid & 1) * 32;   // K staging coords
    int vk = (lane & 31) * 2;                    // V staging: even local key
    int d0 = wave * 16 + (lane >> 5) * 8;

    // prefetch registers (chunk kc): K 4x uint4, V 4x uint4
    uint4 pk0, pk1, pk2, pk3, pv0, pv1, pv2, pv3;
    {   // prefetch chunk 0
        size_t base = (size_t)srow * 3072 + 1024 + h * 64 + sc0;
        pk0 = *(const uint4*)&qkv[base];
        pk1 = *(const uint4*)&qkv[base + 8];
        pk2 = *(const uint4*)&qkv[base + 16];
        pk3 = *(const uint4*)&qkv[base + 24];
        size_t vb0 = (size_t)vk * 3072 + 2048 + h * 64 + d0;
        pv0 = *(const uint4*)&qkv[vb0];
        pv1 = *(const uint4*)&qkv[vb0 + 3072];
        size_t vb1 = (size_t)(64 + vk) * 3072 + 2048 + h * 64 + d0;
        pv2 = *(const uint4*)&qkv[vb1];
        pv3 = *(const uint4*)&qkv[vb1 + 3072];
    }

    for (int kc = 0; kc <= qb; kc += 2) {      // 128 keys per iteration
        __syncthreads();   // prev-iter LDS reads done (covers Q-frag reads at kc=0)
        {   // write prefetched K chunk to LDS
            *(uint4*)&Ks[srow][sc0]      = pk0;
            *(uint4*)&Ks[srow][sc0 + 8]  = pk1;
            *(uint4*)&Ks[srow][sc0 + 16] = pk2;
            *(uint4*)&Ks[srow][sc0 + 24] = pk3;
        }
        {   // write prefetched V chunk TRANSPOSED, key-pairs packed as b32
            const unsigned short* pe0 = (const unsigned short*)&pv0;
            const unsigned short* po0 = (const unsigned short*)&pv1;
            const unsigned short* pe1 = (const unsigned short*)&pv2;
            const unsigned short* po1 = (const unsigned short*)&pv3;
#pragma unroll
            for (int j = 0; j < 8; j++) {
                *(uint32_t*)&Vt[d0 + j][vk]      = (uint32_t)pe0[j] | ((uint32_t)po0[j] << 16);
                *(uint32_t*)&Vt[d0 + j][64 + vk] = (uint32_t)pe1[j] | ((uint32_t)po1[j] << 16);
            }
        }
        __syncthreads();

        if (kc + 2 <= qb) {   // issue next chunk's loads; overlap with compute below
            size_t base = (size_t)((kc + 2) * 64 + srow) * 3072 + 1024 + h * 64 + sc0;
            pk0 = *(const uint4*)&qkv[base];
            pk1 = *(const uint4*)&qkv[base + 8];
            pk2 = *(const uint4*)&qkv[base + 16];
            pk3 = *(const uint4*)&qkv[base + 24];
            size_t vb0 = (size_t)((kc + 2) * 64 + vk) * 3072 + 2048 + h * 64 + d0;
            pv0 = *(const uint4*)&qkv[vb0];
            pv1 = *(const uint4*)&qkv[vb0 + 3072];
            size_t vb1 = (size_t)((kc + 3) * 64 + vk) * 3072 + 2048 + h * 64 + d0;
            pv2 = *(const uint4*)&qkv[vb1];
            pv3 = *(const uint4*)&qkv[vb1 + 3072];
        }

        // ---- S = Q K^T  (16q x 128k per wave) ----
        f32x4 sacc[8] = {};
#pragma unroll
        for (int kt = 0; kt < 8; kt++) {
            short8 bk0 = *(const short8*)&Ks[kt * 16 + lane16][quad * 8];
            short8 bk1 = *(const short8*)&Ks[kt * 16 + lane16][32 + quad * 8];
            sacc[kt] = __builtin_amdgcn_mfma_f32_16x16x32_bf16(aq0, bk0, sacc[kt], 0, 0, 0);
            sacc[kt] = __builtin_amdgcn_mfma_f32_16x16x32_bf16(aq1, bk1, sacc[kt], 0, 0, 0);
        }

        // ---- static-max softmax: p = 2^(s*C1 - C2); mask only on last chunk ----
        bool domask = (kc + 2 > qb);   // wave-uniform
#pragma unroll
        for (int r = 0; r < 4; r++) {
            int qrow = q0 + wave * 16 + quad * 4 + r;
#pragma unroll
            for (int kt = 0; kt < 8; kt++) {
                float s = sacc[kt][r];
                if (domask) {
                    int key = kc * 64 + kt * 16 + lane16;
                    s = (key <= qrow) ? s : -__builtin_inff();
                }
                float p = exp2f(fmaf(s, C1, -C2));   // masked -> 0
                l_part[r] += p;
                Ps[wave][quad * 4 + r][kt * 16 + lane16] = f2b(p);
            }
        }
        // no barrier: Ps is wave-private; in-wave RAW ordered by lgkmcnt

        // ---- O += P V  (A=P rows, B=V^T rows, both key-contiguous) ----
#pragma unroll
        for (int s = 0; s < 4; s++) {
            short8 ap = *(const short8*)&Ps[wave][lane16][s * 32 + quad * 8];
#pragma unroll
            for (int dt = 0; dt < 4; dt++) {
                short8 bv = *(const short8*)&Vt[dt * 16 + lane16][s * 32 + quad * 8];
                Oacc[dt] = __builtin_amdgcn_mfma_f32_16x16x32_bf16(ap, bv, Oacc[dt], 0, 0, 0);
            }
        }
    }

    // deferred l reduction (sum over lane16 key-group) + output
    float invl[4];
#pragma unroll
    for (int r = 0; r < 4; r++) {
        float lf = l_part[r];
        lf += __shfl_xor(lf, 1);
        lf += __shfl_xor(lf, 2);
        lf += __shfl_xor(lf, 4);
        lf += __shfl_xor(lf, 8);
        invl[r] = 1.0f / lf;
    }
#pragma unroll
    for (int dt = 0; dt < 4; dt++) {
#pragma unroll
        for (int r = 0; r < 4; r++) {
            int qrow = q0 + wave * 16 + quad * 4 + r;
            out[(size_t)qrow * 1024 + h * 64 + dt * 16 + lane16] = f2b(Oacc[dt][r] * invl[r]);
        }
    }
}

// ---------- launch ----------
extern "C" void kernel_launch(void* const* d_in, const int* in_sizes, int n_in,
                              void* d_out, int out_size, void* d_ws, size_t ws_size,
                              hipStream_t stream) {
    const float* x      = (const float*)d_in[0];
    const float* w_qkv  = (const float*)d_in[1];
    const float* w_attn = (const float*)d_in[2];
    const float* w_fc   = (const float*)d_in[3];
    const float* w_mlp  = (const float*)d_in[4];
    const float* ln1w   = (const float*)d_in[5];
    const float* ln2w   = (const float*)d_in[6];

    char* ws = (char*)d_ws;   // total 112 MB, no aliasing
    unsigned short* h      = (unsigned short*)(ws + 0);          //  8 MB
    unsigned short* wqkvT  = (unsigned short*)(ws + 8388608);    //  6 MB
    unsigned short* wattnT = (unsigned short*)(ws + 14680064);   //  2 MB
    unsigned short* wfcT   = (unsigned short*)(ws + 16777216);   //  8 MB
    unsigned short* wmlpT  = (unsigned short*)(ws + 25165824);   //  8 MB
    unsigned short* qkv    = (unsigned short*)(ws + 33554432);   // 24 MB
    unsigned short* attno  = (unsigned short*)(ws + 58720256);   //  8 MB
    float*          x2     = (float*)(ws + 67108864);            // 16 MB
    unsigned short* fcact  = (unsigned short*)(ws + 83886080);   // 32 MB
    float* outF = (float*)d_out;

    dim3 tb(32, 8);
    k_transpose_bf16<<<dim3(96, 32),  tb, 0, stream>>>(w_qkv,  wqkvT,  1024, 3072);
    k_transpose_bf16<<<dim3(32, 32),  tb, 0, stream>>>(w_attn, wattnT, 1024, 1024);
    k_transpose_bf16<<<dim3(128, 32), tb, 0, stream>>>(w_fc,   wfcT,   1024, 4096);
    k_transpose_bf16<<<dim3(32, 128), tb, 0, stream>>>(w_mlp,  wmlpT,  4096, 1024);

    k_layernorm<<<4096, 256, 0, stream>>>(x, ln1w, h);
    k_gemm_bt<1, 128><<<dim3(24, 32), 256, 0, stream>>>(h, wqkvT, nullptr, qkv, 4096, 3072, 1024);
    k_attn<<<1024, 256, 0, stream>>>(qkv, attno);
    k_gemm_bt<2, 64><<<dim3(16, 32), 256, 0, stream>>>(attno, wattnT, x, x2, 4096, 1024, 1024);
    k_layernorm<<<4096, 256, 0, stream>>>(x2, ln2w, h);
    k_gemm_bt<3, 128><<<dim3(32, 32), 256, 0, stream>>>(h, wfcT, nullptr, fcact, 4096, 4096, 1024);
    k_gemm_bt<2, 64><<<dim3(16, 32), 256, 0, stream>>>(fcact, wmlpT, x2, outF, 4096, 1024, 4096);
}